// Round 6
// baseline (336.843 us; speedup 1.0000x reference)
//
#include <hip/hip_runtime.h>
#include <hip/hip_bf16.h>

// ---------------------------------------------------------------------------
// GCN 2-layer + mean-pool + linear head. bf16 MFMA GEMMs (f32 accumulate),
// bf16 intermediate storage, binned CSR build, wave-per-node pull aggregation.
//   CSR: bucket_count -> bscan -> partition -> bucket_hist_rp (counts + dinv
//        + in-bucket scan -> rp, no global node scan) -> bucket_scatter
//   wconv: W[k][n] f32 -> Wt[n][k] bf16  (both layers, one launch)
//   gemm_mfma: hs = bf16((A @ W) * dinv[row]);  A f32 (layer1) or bf16 (layer2)
//   agg_wave: r = bf16(relu(dinv*(sum_nbr hs + hs_self) + b))  [1 wave/node]
//   pool -> final head
// ---------------------------------------------------------------------------

#define NBS 9            // 512 nodes per bucket
#define NPB 512
#define PART_TILE 4096   // edges per partition tile (256 thr x 16)

typedef __attribute__((ext_vector_type(8))) short short8;
typedef __attribute__((ext_vector_type(4))) float f32x4;

__device__ __forceinline__ float bf2f(unsigned short u) {
    return __uint_as_float(((unsigned int)u) << 16);
}
__device__ __forceinline__ unsigned short f2bf(float f) {
    unsigned int u = __float_as_uint(f);
    return (unsigned short)((u + 0x7FFFu + ((u >> 16) & 1u)) >> 16);
}
__device__ __forceinline__ float4 bfu4_to_f4(ushort4 v) {
    return make_float4(bf2f(v.x), bf2f(v.y), bf2f(v.z), bf2f(v.w));
}
__device__ __forceinline__ short8 pack_bf8(f32x4 a, f32x4 b) {
    short8 s;
    s[0] = (short)f2bf(a.x); s[1] = (short)f2bf(a.y);
    s[2] = (short)f2bf(a.z); s[3] = (short)f2bf(a.w);
    s[4] = (short)f2bf(b.x); s[5] = (short)f2bf(b.y);
    s[6] = (short)f2bf(b.z); s[7] = (short)f2bf(b.w);
    return s;
}

// ---------------- CSR build ----------------

__global__ __launch_bounds__(256) void bucket_count(const int* __restrict__ dst, int E,
                                                    int* __restrict__ bcnt, int B) {
    __shared__ int h[1024];
    for (int i = threadIdx.x; i < B; i += 256) h[i] = 0;
    __syncthreads();
    int i = blockIdx.x * 256 + threadIdx.x;
    int stride = gridDim.x * 256;
    for (; i < E; i += stride) atomicAdd(&h[dst[i] >> NBS], 1);
    __syncthreads();
    for (int i2 = threadIdx.x; i2 < B; i2 += 256)
        if (h[i2]) atomicAdd(&bcnt[i2], h[i2]);
}

__global__ __launch_bounds__(1024) void bscan_kernel(const int* __restrict__ bcnt,
                                                     int* __restrict__ bptr,
                                                     int* __restrict__ bcur, int B) {
    __shared__ int s[1024];
    int t = threadIdx.x;
    int v = (t < B) ? bcnt[t] : 0;
    s[t] = v;
    __syncthreads();
    for (int off = 1; off < 1024; off <<= 1) {
        int x = (t >= off) ? s[t - off] : 0;
        __syncthreads();
        s[t] += x;
        __syncthreads();
    }
    if (t < B) {
        int excl = s[t] - v;
        bptr[t] = excl;
        bcur[t] = excl;
    }
    if (t == 0) bptr[B] = s[1023];
}

__global__ __launch_bounds__(256) void partition_kernel(const int* __restrict__ src,
                                                        const int* __restrict__ dst, int E,
                                                        int* __restrict__ bcur,
                                                        unsigned int* __restrict__ pairs,
                                                        int B) {
    __shared__ int h[1024];
    __shared__ int rankbase[1024];
    int t = threadIdx.x;
    int tile0 = blockIdx.x * PART_TILE;
    for (int i = t; i < B; i += 256) h[i] = 0;
    __syncthreads();

    int bk[16];
    int rk[16];
    unsigned int pk[16];
#pragma unroll
    for (int j = 0; j < 16; ++j) {
        int idx = tile0 + j * 256 + t;
        bk[j] = -1;
        if (idx < E) {
            int d = dst[idx];
            int s = src[idx];
            bk[j] = d >> NBS;
            pk[j] = ((unsigned int)(d & (NPB - 1)) << 23) | (unsigned int)s;
            rk[j] = atomicAdd(&h[bk[j]], 1);
        }
    }
    __syncthreads();
    for (int i = t; i < B; i += 256) rankbase[i] = h[i] ? atomicAdd(&bcur[i], h[i]) : 0;
    __syncthreads();
#pragma unroll
    for (int j = 0; j < 16; ++j)
        if (bk[j] >= 0) pairs[rankbase[bk[j]] + rk[j]] = pk[j];
}

// counts + dinv + rp (bptr[b] + in-bucket exclusive scan) — no global node scan
__global__ __launch_bounds__(256) void bucket_hist_rp(const unsigned int* __restrict__ pairs,
                                                      const int* __restrict__ bptr,
                                                      int* __restrict__ rp,
                                                      float* __restrict__ dinv, int N, int B) {
    __shared__ int c[NPB];
    __shared__ int sa[NPB];
    __shared__ int sb[NPB];
    int b = blockIdx.x;
    for (int i = threadIdx.x; i < NPB; i += 256) c[i] = 0;
    __syncthreads();
    int s = bptr[b], e = bptr[b + 1];
    for (int i = s + threadIdx.x; i < e; i += 256) atomicAdd(&c[pairs[i] >> 23], 1);
    __syncthreads();
    for (int i = threadIdx.x; i < NPB; i += 256) sa[i] = c[i];
    __syncthreads();
    int* pin = sa;
    int* pout = sb;
    for (int off = 1; off < NPB; off <<= 1) {
        for (int i = threadIdx.x; i < NPB; i += 256)
            pout[i] = pin[i] + ((i >= off) ? pin[i - off] : 0);
        __syncthreads();
        int* tmp = pin; pin = pout; pout = tmp;
    }
    int base = b << NBS;
    for (int i = threadIdx.x; i < NPB; i += 256) {
        int node = base + i;
        if (node < N) {
            rp[node] = s + pin[i] - c[i];  // exclusive within bucket + bucket base
            dinv[node] = rsqrtf((float)c[i] + 1.0f);
        }
    }
    if (b == B - 1 && threadIdx.x == 0) rp[N] = bptr[B];
}

__global__ __launch_bounds__(256) void bucket_scatter(const unsigned int* __restrict__ pairs,
                                                      const int* __restrict__ bptr,
                                                      const int* __restrict__ rp,
                                                      int* __restrict__ col, int N) {
    __shared__ int cur[NPB];
    __shared__ int rpl[NPB];
    int b = blockIdx.x;
    int base = b << NBS;
    for (int i = threadIdx.x; i < NPB; i += 256) {
        cur[i] = 0;
        int node = base + i;
        rpl[i] = (node < N) ? rp[node] : 0;
    }
    __syncthreads();
    int s = bptr[b], e = bptr[b + 1];
    for (int i = s + threadIdx.x; i < e; i += 256) {
        unsigned int p = pairs[i];
        int dL = (int)(p >> 23);
        int sn = (int)(p & 0x7FFFFFu);
        int r = atomicAdd(&cur[dL], 1);
        col[rpl[dL] + r] = sn;
    }
}

// ---------------- GEMM (MFMA) ----------------

// Wt[n][k] = bf16(W[k][n]) for both layers in one launch (<<<256,128>>>)
__global__ void wconv_kernel(const float* __restrict__ W1, const float* __restrict__ W2,
                             unsigned short* __restrict__ Wt1, unsigned short* __restrict__ Wt2) {
    const float* W = (blockIdx.x & 128) ? W2 : W1;
    unsigned short* Wt = (blockIdx.x & 128) ? Wt2 : Wt1;
    int n = blockIdx.x & 127;
    int k = threadIdx.x;
    Wt[n * 128 + k] = f2bf(W[k * 128 + n]);
}

// C[row][c] = bf16((sum_k A[row][k]*W[k][c]) * dinv[row])
template <bool A_F32>
__global__ __launch_bounds__(256) void gemm_mfma(const void* __restrict__ Ap,
                                                 const unsigned short* __restrict__ Wt,
                                                 const float* __restrict__ dinv,
                                                 unsigned short* __restrict__ C, int M) {
    __shared__ unsigned char lds[32768];
    int t = threadIdx.x;
#pragma unroll
    for (int i = 0; i < 8; ++i) {
        int c = t + i * 256;
        int row = c >> 4;
        int b = (c & 15) << 4;
        int4 v = ((const int4*)Wt)[c];
        *(int4*)&lds[row * 256 + (b ^ ((row & 7) << 4))] = v;
    }

    int lane = t & 63;
    int wv = t >> 6;
    int r0 = blockIdx.x * 128 + wv * 32;
    int l15 = lane & 15;
    int kg = lane >> 4;

    short8 af[2][4];
#pragma unroll
    for (int rf = 0; rf < 2; ++rf) {
        int row = r0 + rf * 16 + l15;
        row = row < M ? row : M - 1;
#pragma unroll
        for (int kk = 0; kk < 4; ++kk) {
            size_t eoff = (size_t)row * 128 + kk * 32 + kg * 8;
            if constexpr (A_F32) {
                const float* A = (const float*)Ap;
                f32x4 v0 = __builtin_nontemporal_load((const f32x4*)(A + eoff));
                f32x4 v1 = __builtin_nontemporal_load((const f32x4*)(A + eoff + 4));
                af[rf][kk] = pack_bf8(v0, v1);
            } else {
                af[rf][kk] = *(const short8*)((const unsigned short*)Ap + eoff);
            }
        }
    }
    __syncthreads();

    f32x4 acc[2][8];
#pragma unroll
    for (int rf = 0; rf < 2; ++rf)
#pragma unroll
        for (int cf = 0; cf < 8; ++cf) acc[rf][cf] = (f32x4)(0.f);

#pragma unroll
    for (int cf = 0; cf < 8; ++cf) {
        short8 bfr[4];
#pragma unroll
        for (int kk = 0; kk < 4; ++kk) {
            int brow = cf * 16 + l15;
            int bb = kk * 64 + kg * 16;
            bfr[kk] = *(const short8*)&lds[brow * 256 + (bb ^ ((brow & 7) << 4))];
        }
#pragma unroll
        for (int kk = 0; kk < 4; ++kk) {
#pragma unroll
            for (int rf = 0; rf < 2; ++rf)
                acc[rf][cf] = __builtin_amdgcn_mfma_f32_16x16x32_bf16(af[rf][kk], bfr[kk],
                                                                      acc[rf][cf], 0, 0, 0);
        }
    }

#pragma unroll
    for (int rf = 0; rf < 2; ++rf) {
#pragma unroll
        for (int r = 0; r < 4; ++r) {
            int row = r0 + rf * 16 + kg * 4 + r;
            if (row < M) {
                float dv = dinv[row];
#pragma unroll
                for (int cf = 0; cf < 8; ++cf)
                    C[(size_t)row * 128 + cf * 16 + l15] = f2bf(acc[rf][cf][r] * dv);
            }
        }
    }
}

// ---------------- aggregation / pool / head ----------------

// one 64-lane wave per node; each lane owns 2 bf16 (one u32)
__global__ __launch_bounds__(256) void agg_wave(const unsigned int* __restrict__ h2,
                                                const float* __restrict__ dinv,
                                                const int* __restrict__ rp,
                                                const int* __restrict__ col,
                                                const float* __restrict__ bias,
                                                unsigned int* __restrict__ out2, int N) {
    int g = (int)((blockIdx.x * 256 + threadIdx.x) >> 6);
    int lane = threadIdx.x & 63;
    if (g >= N) return;
    unsigned int sv = h2[(size_t)g * 64 + lane];  // self (hs_i)
    float ax = __uint_as_float(sv << 16);
    float ay = __uint_as_float(sv & 0xFFFF0000u);
    int e = rp[g], end = rp[g + 1];
    for (; e + 7 < end; e += 8) {
        int j0 = __builtin_nontemporal_load(&col[e + 0]);
        int j1 = __builtin_nontemporal_load(&col[e + 1]);
        int j2 = __builtin_nontemporal_load(&col[e + 2]);
        int j3 = __builtin_nontemporal_load(&col[e + 3]);
        int j4 = __builtin_nontemporal_load(&col[e + 4]);
        int j5 = __builtin_nontemporal_load(&col[e + 5]);
        int j6 = __builtin_nontemporal_load(&col[e + 6]);
        int j7 = __builtin_nontemporal_load(&col[e + 7]);
        unsigned int v0 = h2[(size_t)j0 * 64 + lane];
        unsigned int v1 = h2[(size_t)j1 * 64 + lane];
        unsigned int v2 = h2[(size_t)j2 * 64 + lane];
        unsigned int v3 = h2[(size_t)j3 * 64 + lane];
        unsigned int v4 = h2[(size_t)j4 * 64 + lane];
        unsigned int v5 = h2[(size_t)j5 * 64 + lane];
        unsigned int v6 = h2[(size_t)j6 * 64 + lane];
        unsigned int v7 = h2[(size_t)j7 * 64 + lane];
        ax += __uint_as_float(v0 << 16) + __uint_as_float(v1 << 16);
        ay += __uint_as_float(v0 & 0xFFFF0000u) + __uint_as_float(v1 & 0xFFFF0000u);
        ax += __uint_as_float(v2 << 16) + __uint_as_float(v3 << 16);
        ay += __uint_as_float(v2 & 0xFFFF0000u) + __uint_as_float(v3 & 0xFFFF0000u);
        ax += __uint_as_float(v4 << 16) + __uint_as_float(v5 << 16);
        ay += __uint_as_float(v4 & 0xFFFF0000u) + __uint_as_float(v5 & 0xFFFF0000u);
        ax += __uint_as_float(v6 << 16) + __uint_as_float(v7 << 16);
        ay += __uint_as_float(v6 & 0xFFFF0000u) + __uint_as_float(v7 & 0xFFFF0000u);
    }
    for (; e < end; ++e) {
        int j = __builtin_nontemporal_load(&col[e]);
        unsigned int v = h2[(size_t)j * 64 + lane];
        ax += __uint_as_float(v << 16);
        ay += __uint_as_float(v & 0xFFFF0000u);
    }
    float dv = dinv[g];
    float2 bb = ((const float2*)bias)[lane];
    float ox = fmaxf(fmaf(ax, dv, bb.x), 0.f);
    float oy = fmaxf(fmaf(ay, dv, bb.y), 0.f);
    unsigned int o = (unsigned int)f2bf(ox) | ((unsigned int)f2bf(oy) << 16);
    __builtin_nontemporal_store(o, &out2[(size_t)g * 64 + lane]);
}

__global__ __launch_bounds__(256) void pool_bf16(const unsigned short* __restrict__ r2,
                                                 const int* __restrict__ batch,
                                                 float* __restrict__ ps,
                                                 int* __restrict__ pc, int N) {
    int grp = (int)((blockIdx.x * 256 + threadIdx.x) >> 5);
    int lane = threadIdx.x & 31;
    int n0 = grp * 32;
    if (n0 >= N) return;
    int n1 = min(n0 + 32, N);
    const ushort4* r4 = (const ushort4*)r2;
    float4 acc = make_float4(0.f, 0.f, 0.f, 0.f);
    int curg = batch[n0];
    int cnt = 0;
    for (int n = n0; n < n1; ++n) {
        int gph = batch[n];
        if (gph != curg) {
            atomicAdd(&ps[curg * 128 + lane * 4 + 0], acc.x);
            atomicAdd(&ps[curg * 128 + lane * 4 + 1], acc.y);
            atomicAdd(&ps[curg * 128 + lane * 4 + 2], acc.z);
            atomicAdd(&ps[curg * 128 + lane * 4 + 3], acc.w);
            if (lane == 0) atomicAdd(&pc[curg], cnt);
            acc = make_float4(0.f, 0.f, 0.f, 0.f);
            cnt = 0;
            curg = gph;
        }
        float4 v = bfu4_to_f4(r4[(size_t)n * 32 + lane]);
        acc.x += v.x;
        acc.y += v.y;
        acc.z += v.z;
        acc.w += v.w;
        cnt++;
    }
    atomicAdd(&ps[curg * 128 + lane * 4 + 0], acc.x);
    atomicAdd(&ps[curg * 128 + lane * 4 + 1], acc.y);
    atomicAdd(&ps[curg * 128 + lane * 4 + 2], acc.z);
    atomicAdd(&ps[curg * 128 + lane * 4 + 3], acc.w);
    if (lane == 0) atomicAdd(&pc[curg], cnt);
}

__global__ __launch_bounds__(256) void final_kernel(const float* __restrict__ ps,
                                                    const int* __restrict__ pc,
                                                    const float* __restrict__ Wlin,
                                                    const float* __restrict__ blin,
                                                    float* __restrict__ out, int G) {
    int g = (int)((blockIdx.x * 256 + threadIdx.x) >> 6);
    int lane = threadIdx.x & 63;
    if (g >= G) return;
    float2 s = ((const float2*)ps)[g * 64 + lane];
    float2 w = ((const float2*)Wlin)[lane];
    float v = s.x * w.x + s.y * w.y;
#pragma unroll
    for (int off = 32; off > 0; off >>= 1) v += __shfl_down(v, off);
    if (lane == 0) {
        float c = (float)max(pc[g], 1);
        out[g] = v / c + blin[0];
    }
}

extern "C" void kernel_launch(void* const* d_in, const int* in_sizes, int n_in,
                              void* d_out, int out_size, void* d_ws, size_t ws_size,
                              hipStream_t stream) {
    const float* x    = (const float*)d_in[0];
    const float* W1   = (const float*)d_in[1];
    const float* b1   = (const float*)d_in[2];
    const float* W2   = (const float*)d_in[3];
    const float* b2   = (const float*)d_in[4];
    const float* Wlin = (const float*)d_in[5];
    const float* blin = (const float*)d_in[6];
    const int*   ei   = (const int*)d_in[7];   // [2, E]
    const int*   batch= (const int*)d_in[8];   // [N]

    const int N = in_sizes[0] / 128;
    const int E = in_sizes[7] / 2;
    const int G = out_size;
    const int B = (N + NPB - 1) >> NBS;

    const int* srcp = ei;
    const int* dstp = ei + E;

    char* w = (char*)d_ws;
    size_t off = 0;
    auto carve = [&](size_t bytes) {
        size_t o = off;
        off = (off + bytes + 255) & ~(size_t)255;
        return (void*)(w + o);
    };
    unsigned short* bufA = (unsigned short*)carve((size_t)N * 128 * 2);
    unsigned short* bufB = (unsigned short*)carve((size_t)N * 128 * 2);
    float* dinv = (float*)carve((size_t)N * 4);
    int*   rp   = (int*)carve((size_t)(N + 1) * 4);
    int*   col  = (int*)carve((size_t)E * 4);
    unsigned int* pairs = (unsigned int*)carve((size_t)E * 4);
    int*   bcnt = (int*)carve((size_t)(B + 1) * 4);
    int*   bptr = (int*)carve((size_t)(B + 1) * 4);
    int*   bcur = (int*)carve((size_t)(B + 1) * 4);
    unsigned short* Wt1 = (unsigned short*)carve(128 * 128 * 2);
    unsigned short* Wt2 = (unsigned short*)carve(128 * 128 * 2);
    float* ps   = (float*)carve((size_t)G * 128 * 4);
    int*   pc   = (int*)carve((size_t)G * 4);
    (void)ws_size;

    const int ntiles = (E + PART_TILE - 1) / PART_TILE;

    // CSR build (binned; rp computed per-bucket, no global node scan)
    hipMemsetAsync(bcnt, 0, (size_t)(B + 1) * 4, stream);
    bucket_count<<<1024, 256, 0, stream>>>(dstp, E, bcnt, B);
    bscan_kernel<<<1, 1024, 0, stream>>>(bcnt, bptr, bcur, B);
    partition_kernel<<<ntiles, 256, 0, stream>>>(srcp, dstp, E, bcur, pairs, B);
    bucket_hist_rp<<<B, 256, 0, stream>>>(pairs, bptr, rp, dinv, N, B);
    bucket_scatter<<<B, 256, 0, stream>>>(pairs, bptr, rp, col, N);

    // weight transpose+convert (both layers)
    wconv_kernel<<<256, 128, 0, stream>>>(W1, W2, Wt1, Wt2);

    const int gemm_grid = (N + 127) / 128;
    const int agg_grid  = (int)(((size_t)N * 64 + 255) / 256);

    // layer 1
    gemm_mfma<true><<<gemm_grid, 256, 0, stream>>>(x, Wt1, dinv, bufA, N);
    agg_wave<<<agg_grid, 256, 0, stream>>>((const unsigned int*)bufA, dinv, rp, col, b1,
                                           (unsigned int*)bufB, N);
    // layer 2
    gemm_mfma<false><<<gemm_grid, 256, 0, stream>>>(bufB, Wt2, dinv, bufA, N);
    agg_wave<<<agg_grid, 256, 0, stream>>>((const unsigned int*)bufA, dinv, rp, col, b2,
                                           (unsigned int*)bufB, N);

    // pooling
    hipMemsetAsync(ps, 0, (size_t)G * 128 * 4, stream);
    hipMemsetAsync(pc, 0, (size_t)G * 4, stream);
    const int ngrp = (N + 31) / 32;
    pool_bf16<<<(int)(((size_t)ngrp * 32 + 255) / 256), 256, 0, stream>>>(bufB, batch, ps, pc, N);

    final_kernel<<<(G * 64 + 255) / 256, 256, 0, stream>>>(ps, pc, Wlin, blin, (float*)d_out, G);
}

// Round 7
// 290.691 us; speedup vs baseline: 1.1588x; 1.1588x over previous
//
#include <hip/hip_runtime.h>
#include <hip/hip_bf16.h>

// ---------------------------------------------------------------------------
// GCN 2-layer + mean-pool + linear head. bf16 MFMA GEMMs (f32 accumulate),
// bf16 intermediate storage, binned CSR build, degree-sorted 16-lane-per-node
// pull aggregation (dwordx4 gathers).
//   CSR: bucket_count -> bscan -> partition -> bucket_hist_rp -> bucket_scatter
//   perm: degree counting-sort (64 bins) -> process nodes in degree order so
//         the 4 nodes sharing a wave have near-equal degree (no divergence)
//   gemm_mfma: hs = bf16((A @ W) * dinv[row])
//   agg_q16: r = bf16(relu(dinv*(sum_nbr hs + hs_self) + b))  [16 lanes/node]
//   pool -> final head
// ---------------------------------------------------------------------------

#define NBS 9            // 512 nodes per bucket
#define NPB 512
#define PART_TILE 4096   // edges per partition tile (256 thr x 16)
#define DBINS 64

typedef __attribute__((ext_vector_type(8))) short short8;
typedef __attribute__((ext_vector_type(4))) float f32x4;

__device__ __forceinline__ float bf2f(unsigned short u) {
    return __uint_as_float(((unsigned int)u) << 16);
}
__device__ __forceinline__ unsigned short f2bf(float f) {
    unsigned int u = __float_as_uint(f);
    return (unsigned short)((u + 0x7FFFu + ((u >> 16) & 1u)) >> 16);
}
__device__ __forceinline__ float4 bfu4_to_f4(ushort4 v) {
    return make_float4(bf2f(v.x), bf2f(v.y), bf2f(v.z), bf2f(v.w));
}
__device__ __forceinline__ short8 pack_bf8(f32x4 a, f32x4 b) {
    short8 s;
    s[0] = (short)f2bf(a.x); s[1] = (short)f2bf(a.y);
    s[2] = (short)f2bf(a.z); s[3] = (short)f2bf(a.w);
    s[4] = (short)f2bf(b.x); s[5] = (short)f2bf(b.y);
    s[6] = (short)f2bf(b.z); s[7] = (short)f2bf(b.w);
    return s;
}
__device__ __forceinline__ void acc8(int4 v, float* a) {
    a[0] += __uint_as_float(((unsigned int)v.x) << 16);
    a[1] += __uint_as_float(((unsigned int)v.x) & 0xFFFF0000u);
    a[2] += __uint_as_float(((unsigned int)v.y) << 16);
    a[3] += __uint_as_float(((unsigned int)v.y) & 0xFFFF0000u);
    a[4] += __uint_as_float(((unsigned int)v.z) << 16);
    a[5] += __uint_as_float(((unsigned int)v.z) & 0xFFFF0000u);
    a[6] += __uint_as_float(((unsigned int)v.w) << 16);
    a[7] += __uint_as_float(((unsigned int)v.w) & 0xFFFF0000u);
}
__device__ __forceinline__ unsigned int pack2(float x, float y) {
    return (unsigned int)f2bf(x) | ((unsigned int)f2bf(y) << 16);
}

// ---------------- CSR build ----------------

__global__ __launch_bounds__(256) void bucket_count(const int* __restrict__ dst, int E,
                                                    int* __restrict__ bcnt, int B) {
    __shared__ int h[1024];
    for (int i = threadIdx.x; i < B; i += 256) h[i] = 0;
    __syncthreads();
    int i = blockIdx.x * 256 + threadIdx.x;
    int stride = gridDim.x * 256;
    for (; i < E; i += stride) atomicAdd(&h[dst[i] >> NBS], 1);
    __syncthreads();
    for (int i2 = threadIdx.x; i2 < B; i2 += 256)
        if (h[i2]) atomicAdd(&bcnt[i2], h[i2]);
}

__global__ __launch_bounds__(1024) void bscan_kernel(const int* __restrict__ bcnt,
                                                     int* __restrict__ bptr,
                                                     int* __restrict__ bcur, int B) {
    __shared__ int s[1024];
    int t = threadIdx.x;
    int v = (t < B) ? bcnt[t] : 0;
    s[t] = v;
    __syncthreads();
    for (int off = 1; off < 1024; off <<= 1) {
        int x = (t >= off) ? s[t - off] : 0;
        __syncthreads();
        s[t] += x;
        __syncthreads();
    }
    if (t < B) {
        int excl = s[t] - v;
        bptr[t] = excl;
        bcur[t] = excl;
    }
    if (t == 0) bptr[B] = s[1023];
}

__global__ __launch_bounds__(256) void partition_kernel(const int* __restrict__ src,
                                                        const int* __restrict__ dst, int E,
                                                        int* __restrict__ bcur,
                                                        unsigned int* __restrict__ pairs,
                                                        int B) {
    __shared__ int h[1024];
    __shared__ int rankbase[1024];
    int t = threadIdx.x;
    int tile0 = blockIdx.x * PART_TILE;
    for (int i = t; i < B; i += 256) h[i] = 0;
    __syncthreads();

    int bk[16];
    int rk[16];
    unsigned int pk[16];
#pragma unroll
    for (int j = 0; j < 16; ++j) {
        int idx = tile0 + j * 256 + t;
        bk[j] = -1;
        if (idx < E) {
            int d = dst[idx];
            int s = src[idx];
            bk[j] = d >> NBS;
            pk[j] = ((unsigned int)(d & (NPB - 1)) << 23) | (unsigned int)s;
            rk[j] = atomicAdd(&h[bk[j]], 1);
        }
    }
    __syncthreads();
    for (int i = t; i < B; i += 256) rankbase[i] = h[i] ? atomicAdd(&bcur[i], h[i]) : 0;
    __syncthreads();
#pragma unroll
    for (int j = 0; j < 16; ++j)
        if (bk[j] >= 0) pairs[rankbase[bk[j]] + rk[j]] = pk[j];
}

// counts + dinv + rp (bptr[b] + in-bucket exclusive scan)
__global__ __launch_bounds__(256) void bucket_hist_rp(const unsigned int* __restrict__ pairs,
                                                      const int* __restrict__ bptr,
                                                      int* __restrict__ rp,
                                                      float* __restrict__ dinv, int N, int B) {
    __shared__ int c[NPB];
    __shared__ int sa[NPB];
    __shared__ int sb[NPB];
    int b = blockIdx.x;
    for (int i = threadIdx.x; i < NPB; i += 256) c[i] = 0;
    __syncthreads();
    int s = bptr[b], e = bptr[b + 1];
    for (int i = s + threadIdx.x; i < e; i += 256) atomicAdd(&c[pairs[i] >> 23], 1);
    __syncthreads();
    for (int i = threadIdx.x; i < NPB; i += 256) sa[i] = c[i];
    __syncthreads();
    int* pin = sa;
    int* pout = sb;
    for (int off = 1; off < NPB; off <<= 1) {
        for (int i = threadIdx.x; i < NPB; i += 256)
            pout[i] = pin[i] + ((i >= off) ? pin[i - off] : 0);
        __syncthreads();
        int* tmp = pin; pin = pout; pout = tmp;
    }
    int base = b << NBS;
    for (int i = threadIdx.x; i < NPB; i += 256) {
        int node = base + i;
        if (node < N) {
            rp[node] = s + pin[i] - c[i];
            dinv[node] = rsqrtf((float)c[i] + 1.0f);
        }
    }
    if (b == B - 1 && threadIdx.x == 0) rp[N] = bptr[B];
}

__global__ __launch_bounds__(256) void bucket_scatter(const unsigned int* __restrict__ pairs,
                                                      const int* __restrict__ bptr,
                                                      const int* __restrict__ rp,
                                                      int* __restrict__ col, int N) {
    __shared__ int cur[NPB];
    __shared__ int rpl[NPB];
    int b = blockIdx.x;
    int base = b << NBS;
    for (int i = threadIdx.x; i < NPB; i += 256) {
        cur[i] = 0;
        int node = base + i;
        rpl[i] = (node < N) ? rp[node] : 0;
    }
    __syncthreads();
    int s = bptr[b], e = bptr[b + 1];
    for (int i = s + threadIdx.x; i < e; i += 256) {
        unsigned int p = pairs[i];
        int dL = (int)(p >> 23);
        int sn = (int)(p & 0x7FFFFFu);
        int r = atomicAdd(&cur[dL], 1);
        col[rpl[dL] + r] = sn;
    }
}

// ---------------- degree permutation (counting sort, 64 bins) ----------------

__global__ __launch_bounds__(256) void deg_hist(const int* __restrict__ rp, int N,
                                                int* __restrict__ dh) {
    __shared__ int h[DBINS];
    if (threadIdx.x < DBINS) h[threadIdx.x] = 0;
    __syncthreads();
    int i = blockIdx.x * 256 + threadIdx.x;
    if (i < N) {
        int d = min(rp[i + 1] - rp[i], DBINS - 1);
        atomicAdd(&h[d], 1);
    }
    __syncthreads();
    if (threadIdx.x < DBINS && h[threadIdx.x]) atomicAdd(&dh[threadIdx.x], h[threadIdx.x]);
}

__global__ void deg_scan(const int* __restrict__ dh, int* __restrict__ dcur) {
    __shared__ int s[DBINS];
    int t = threadIdx.x;
    int v = dh[t];
    s[t] = v;
    __syncthreads();
    for (int off = 1; off < DBINS; off <<= 1) {
        int x = (t >= off) ? s[t - off] : 0;
        __syncthreads();
        s[t] += x;
        __syncthreads();
    }
    dcur[t] = s[t] - v;  // exclusive
}

__global__ __launch_bounds__(256) void deg_scatter(const int* __restrict__ rp, int N,
                                                   int* __restrict__ dcur,
                                                   int* __restrict__ perm) {
    __shared__ int h[DBINS];
    __shared__ int base[DBINS];
    if (threadIdx.x < DBINS) h[threadIdx.x] = 0;
    __syncthreads();
    int i = blockIdx.x * 256 + threadIdx.x;
    int d = -1, r = 0;
    if (i < N) {
        d = min(rp[i + 1] - rp[i], DBINS - 1);
        r = atomicAdd(&h[d], 1);
    }
    __syncthreads();
    if (threadIdx.x < DBINS) base[threadIdx.x] = h[threadIdx.x] ? atomicAdd(&dcur[threadIdx.x], h[threadIdx.x]) : 0;
    __syncthreads();
    if (i < N) perm[base[d] + r] = i;
}

// ---------------- GEMM (MFMA) ----------------

__global__ void wconv_kernel(const float* __restrict__ W1, const float* __restrict__ W2,
                             unsigned short* __restrict__ Wt1, unsigned short* __restrict__ Wt2) {
    const float* W = (blockIdx.x & 128) ? W2 : W1;
    unsigned short* Wt = (blockIdx.x & 128) ? Wt2 : Wt1;
    int n = blockIdx.x & 127;
    int k = threadIdx.x;
    Wt[n * 128 + k] = f2bf(W[k * 128 + n]);
}

template <bool A_F32>
__global__ __launch_bounds__(256) void gemm_mfma(const void* __restrict__ Ap,
                                                 const unsigned short* __restrict__ Wt,
                                                 const float* __restrict__ dinv,
                                                 unsigned short* __restrict__ C, int M) {
    __shared__ unsigned char lds[32768];
    int t = threadIdx.x;
#pragma unroll
    for (int i = 0; i < 8; ++i) {
        int c = t + i * 256;
        int row = c >> 4;
        int b = (c & 15) << 4;
        int4 v = ((const int4*)Wt)[c];
        *(int4*)&lds[row * 256 + (b ^ ((row & 7) << 4))] = v;
    }

    int lane = t & 63;
    int wv = t >> 6;
    int r0 = blockIdx.x * 128 + wv * 32;
    int l15 = lane & 15;
    int kg = lane >> 4;

    short8 af[2][4];
#pragma unroll
    for (int rf = 0; rf < 2; ++rf) {
        int row = r0 + rf * 16 + l15;
        row = row < M ? row : M - 1;
#pragma unroll
        for (int kk = 0; kk < 4; ++kk) {
            size_t eoff = (size_t)row * 128 + kk * 32 + kg * 8;
            if constexpr (A_F32) {
                const float* A = (const float*)Ap;
                f32x4 v0 = __builtin_nontemporal_load((const f32x4*)(A + eoff));
                f32x4 v1 = __builtin_nontemporal_load((const f32x4*)(A + eoff + 4));
                af[rf][kk] = pack_bf8(v0, v1);
            } else {
                af[rf][kk] = *(const short8*)((const unsigned short*)Ap + eoff);
            }
        }
    }
    __syncthreads();

    f32x4 acc[2][8];
#pragma unroll
    for (int rf = 0; rf < 2; ++rf)
#pragma unroll
        for (int cf = 0; cf < 8; ++cf) acc[rf][cf] = (f32x4)(0.f);

#pragma unroll
    for (int cf = 0; cf < 8; ++cf) {
        short8 bfr[4];
#pragma unroll
        for (int kk = 0; kk < 4; ++kk) {
            int brow = cf * 16 + l15;
            int bb = kk * 64 + kg * 16;
            bfr[kk] = *(const short8*)&lds[brow * 256 + (bb ^ ((brow & 7) << 4))];
        }
#pragma unroll
        for (int kk = 0; kk < 4; ++kk) {
#pragma unroll
            for (int rf = 0; rf < 2; ++rf)
                acc[rf][cf] = __builtin_amdgcn_mfma_f32_16x16x32_bf16(af[rf][kk], bfr[kk],
                                                                      acc[rf][cf], 0, 0, 0);
        }
    }

#pragma unroll
    for (int rf = 0; rf < 2; ++rf) {
#pragma unroll
        for (int r = 0; r < 4; ++r) {
            int row = r0 + rf * 16 + kg * 4 + r;
            if (row < M) {
                float dv = dinv[row];
#pragma unroll
                for (int cf = 0; cf < 8; ++cf)
                    C[(size_t)row * 128 + cf * 16 + l15] = f2bf(acc[rf][cf][r] * dv);
            }
        }
    }
}

// ---------------- aggregation / pool / head ----------------

// 16 lanes per node (dwordx4 row segments), 4 nodes/wave, degree-sorted order
__global__ __launch_bounds__(256) void agg_q16(const unsigned short* __restrict__ hs,
                                               const float* __restrict__ dinv,
                                               const int* __restrict__ rp,
                                               const int* __restrict__ col,
                                               const int* __restrict__ perm,
                                               const float* __restrict__ bias,
                                               unsigned short* __restrict__ out, int N) {
    int q = (int)((blockIdx.x * 256 + threadIdx.x) >> 4);
    int l = threadIdx.x & 15;
    if (q >= N) return;
    int g = perm[q];
    const int4* h4 = (const int4*)hs;

    float a[8];
    {
        int4 sv = h4[(size_t)g * 16 + l];  // self (hs_i)
        a[0] = __uint_as_float(((unsigned int)sv.x) << 16);
        a[1] = __uint_as_float(((unsigned int)sv.x) & 0xFFFF0000u);
        a[2] = __uint_as_float(((unsigned int)sv.y) << 16);
        a[3] = __uint_as_float(((unsigned int)sv.y) & 0xFFFF0000u);
        a[4] = __uint_as_float(((unsigned int)sv.z) << 16);
        a[5] = __uint_as_float(((unsigned int)sv.z) & 0xFFFF0000u);
        a[6] = __uint_as_float(((unsigned int)sv.w) << 16);
        a[7] = __uint_as_float(((unsigned int)sv.w) & 0xFFFF0000u);
    }

    int e = rp[g], end = rp[g + 1];
    for (; e + 7 < end; e += 8) {
        int j0 = col[e + 0], j1 = col[e + 1], j2 = col[e + 2], j3 = col[e + 3];
        int j4 = col[e + 4], j5 = col[e + 5], j6 = col[e + 6], j7 = col[e + 7];
        int4 v0 = h4[(size_t)j0 * 16 + l];
        int4 v1 = h4[(size_t)j1 * 16 + l];
        int4 v2 = h4[(size_t)j2 * 16 + l];
        int4 v3 = h4[(size_t)j3 * 16 + l];
        int4 v4 = h4[(size_t)j4 * 16 + l];
        int4 v5 = h4[(size_t)j5 * 16 + l];
        int4 v6 = h4[(size_t)j6 * 16 + l];
        int4 v7 = h4[(size_t)j7 * 16 + l];
        acc8(v0, a); acc8(v1, a); acc8(v2, a); acc8(v3, a);
        acc8(v4, a); acc8(v5, a); acc8(v6, a); acc8(v7, a);
    }
    for (; e + 1 < end; e += 2) {
        int j0 = col[e], j1 = col[e + 1];
        int4 v0 = h4[(size_t)j0 * 16 + l];
        int4 v1 = h4[(size_t)j1 * 16 + l];
        acc8(v0, a); acc8(v1, a);
    }
    if (e < end) {
        int j = col[e];
        acc8(h4[(size_t)j * 16 + l], a);
    }

    float dv = dinv[g];
    float4 b0 = ((const float4*)bias)[l * 2];
    float4 b1 = ((const float4*)bias)[l * 2 + 1];
    int4 o;
    o.x = (int)pack2(fmaxf(fmaf(a[0], dv, b0.x), 0.f), fmaxf(fmaf(a[1], dv, b0.y), 0.f));
    o.y = (int)pack2(fmaxf(fmaf(a[2], dv, b0.z), 0.f), fmaxf(fmaf(a[3], dv, b0.w), 0.f));
    o.z = (int)pack2(fmaxf(fmaf(a[4], dv, b1.x), 0.f), fmaxf(fmaf(a[5], dv, b1.y), 0.f));
    o.w = (int)pack2(fmaxf(fmaf(a[6], dv, b1.z), 0.f), fmaxf(fmaf(a[7], dv, b1.w), 0.f));
    ((int4*)out)[(size_t)g * 16 + l] = o;
}

__global__ __launch_bounds__(256) void pool_bf16(const unsigned short* __restrict__ r2,
                                                 const int* __restrict__ batch,
                                                 float* __restrict__ ps,
                                                 int* __restrict__ pc, int N) {
    int grp = (int)((blockIdx.x * 256 + threadIdx.x) >> 5);
    int lane = threadIdx.x & 31;
    int n0 = grp * 32;
    if (n0 >= N) return;
    int n1 = min(n0 + 32, N);
    const ushort4* r4 = (const ushort4*)r2;
    float4 acc = make_float4(0.f, 0.f, 0.f, 0.f);
    int curg = batch[n0];
    int cnt = 0;
    for (int n = n0; n < n1; ++n) {
        int gph = batch[n];
        if (gph != curg) {
            atomicAdd(&ps[curg * 128 + lane * 4 + 0], acc.x);
            atomicAdd(&ps[curg * 128 + lane * 4 + 1], acc.y);
            atomicAdd(&ps[curg * 128 + lane * 4 + 2], acc.z);
            atomicAdd(&ps[curg * 128 + lane * 4 + 3], acc.w);
            if (lane == 0) atomicAdd(&pc[curg], cnt);
            acc = make_float4(0.f, 0.f, 0.f, 0.f);
            cnt = 0;
            curg = gph;
        }
        float4 v = bfu4_to_f4(r4[(size_t)n * 32 + lane]);
        acc.x += v.x;
        acc.y += v.y;
        acc.z += v.z;
        acc.w += v.w;
        cnt++;
    }
    atomicAdd(&ps[curg * 128 + lane * 4 + 0], acc.x);
    atomicAdd(&ps[curg * 128 + lane * 4 + 1], acc.y);
    atomicAdd(&ps[curg * 128 + lane * 4 + 2], acc.z);
    atomicAdd(&ps[curg * 128 + lane * 4 + 3], acc.w);
    if (lane == 0) atomicAdd(&pc[curg], cnt);
}

__global__ __launch_bounds__(256) void final_kernel(const float* __restrict__ ps,
                                                    const int* __restrict__ pc,
                                                    const float* __restrict__ Wlin,
                                                    const float* __restrict__ blin,
                                                    float* __restrict__ out, int G) {
    int g = (int)((blockIdx.x * 256 + threadIdx.x) >> 6);
    int lane = threadIdx.x & 63;
    if (g >= G) return;
    float2 s = ((const float2*)ps)[g * 64 + lane];
    float2 w = ((const float2*)Wlin)[lane];
    float v = s.x * w.x + s.y * w.y;
#pragma unroll
    for (int off = 32; off > 0; off >>= 1) v += __shfl_down(v, off);
    if (lane == 0) {
        float c = (float)max(pc[g], 1);
        out[g] = v / c + blin[0];
    }
}

extern "C" void kernel_launch(void* const* d_in, const int* in_sizes, int n_in,
                              void* d_out, int out_size, void* d_ws, size_t ws_size,
                              hipStream_t stream) {
    const float* x    = (const float*)d_in[0];
    const float* W1   = (const float*)d_in[1];
    const float* b1   = (const float*)d_in[2];
    const float* W2   = (const float*)d_in[3];
    const float* b2   = (const float*)d_in[4];
    const float* Wlin = (const float*)d_in[5];
    const float* blin = (const float*)d_in[6];
    const int*   ei   = (const int*)d_in[7];   // [2, E]
    const int*   batch= (const int*)d_in[8];   // [N]

    const int N = in_sizes[0] / 128;
    const int E = in_sizes[7] / 2;
    const int G = out_size;
    const int B = (N + NPB - 1) >> NBS;

    const int* srcp = ei;
    const int* dstp = ei + E;

    char* w = (char*)d_ws;
    size_t off = 0;
    auto carve = [&](size_t bytes) {
        size_t o = off;
        off = (off + bytes + 255) & ~(size_t)255;
        return (void*)(w + o);
    };
    unsigned short* bufA = (unsigned short*)carve((size_t)N * 128 * 2);
    unsigned short* bufB = (unsigned short*)carve((size_t)N * 128 * 2);
    float* dinv = (float*)carve((size_t)N * 4);
    int*   rp   = (int*)carve((size_t)(N + 1) * 4);
    int*   col  = (int*)carve((size_t)E * 4);
    unsigned int* pairs = (unsigned int*)carve((size_t)E * 4);
    int*   bcnt = (int*)carve((size_t)(B + 1) * 4);
    int*   bptr = (int*)carve((size_t)(B + 1) * 4);
    int*   bcur = (int*)carve((size_t)(B + 1) * 4);
    int*   perm = (int*)carve((size_t)N * 4);
    int*   dh   = (int*)carve(DBINS * 4);
    int*   dcur = (int*)carve(DBINS * 4);
    unsigned short* Wt1 = (unsigned short*)carve(128 * 128 * 2);
    unsigned short* Wt2 = (unsigned short*)carve(128 * 128 * 2);
    float* ps   = (float*)carve((size_t)G * 128 * 4);
    int*   pc   = (int*)carve((size_t)G * 4);
    (void)ws_size;

    const int ntiles = (E + PART_TILE - 1) / PART_TILE;
    const int nblk = (N + 255) / 256;

    // CSR build (binned)
    hipMemsetAsync(bcnt, 0, (size_t)(B + 1) * 4, stream);
    bucket_count<<<1024, 256, 0, stream>>>(dstp, E, bcnt, B);
    bscan_kernel<<<1, 1024, 0, stream>>>(bcnt, bptr, bcur, B);
    partition_kernel<<<ntiles, 256, 0, stream>>>(srcp, dstp, E, bcur, pairs, B);
    bucket_hist_rp<<<B, 256, 0, stream>>>(pairs, bptr, rp, dinv, N, B);
    bucket_scatter<<<B, 256, 0, stream>>>(pairs, bptr, rp, col, N);

    // degree permutation
    hipMemsetAsync(dh, 0, DBINS * 4, stream);
    deg_hist<<<nblk, 256, 0, stream>>>(rp, N, dh);
    deg_scan<<<1, DBINS, 0, stream>>>(dh, dcur);
    deg_scatter<<<nblk, 256, 0, stream>>>(rp, N, dcur, perm);

    // weight transpose+convert (both layers)
    wconv_kernel<<<256, 128, 0, stream>>>(W1, W2, Wt1, Wt2);

    const int gemm_grid = (N + 127) / 128;
    const int agg_grid  = (int)(((size_t)N * 16 + 255) / 256);

    // layer 1
    gemm_mfma<true><<<gemm_grid, 256, 0, stream>>>(x, Wt1, dinv, bufA, N);
    agg_q16<<<agg_grid, 256, 0, stream>>>(bufA, dinv, rp, col, perm, b1, bufB, N);
    // layer 2
    gemm_mfma<false><<<gemm_grid, 256, 0, stream>>>(bufB, Wt2, dinv, bufA, N);
    agg_q16<<<agg_grid, 256, 0, stream>>>(bufA, dinv, rp, col, perm, b2, bufB, N);

    // pooling
    hipMemsetAsync(ps, 0, (size_t)G * 128 * 4, stream);
    hipMemsetAsync(pc, 0, (size_t)G * 4, stream);
    const int ngrp = (N + 31) / 32;
    pool_bf16<<<(int)(((size_t)ngrp * 32 + 255) / 256), 256, 0, stream>>>(bufB, batch, ps, pc, N);

    final_kernel<<<(G * 64 + 255) / 256, 256, 0, stream>>>(ps, pc, Wlin, blin, (float*)d_out, G);
}

// Round 8
// 283.503 us; speedup vs baseline: 1.1881x; 1.0254x over previous
//
#include <hip/hip_runtime.h>
#include <hip/hip_bf16.h>

// ---------------------------------------------------------------------------
// GCN 2-layer + mean-pool + linear head. bf16 MFMA GEMMs (f32 accumulate),
// bf16 intermediate storage, binned CSR build, degree-sorted (descending)
// 16-lane-per-node pull aggregation (dwordx4 gathers).
//   CSR: bucket_count -> bscan -> partition -> bucket_finalize (LDS-staged
//        hist+scan+rp+dinv+scatter in one kernel)
//   perm: degree counting-sort (64 bins); agg processes perm DESCENDING so
//         heavy nodes launch first (no low-occupancy drain tail)
//   gemm_mfma: hs = bf16((A @ W) * dinv[row])
//   agg_q16: r = bf16(relu(dinv*(sum_nbr hs + hs_self) + b))  [16 lanes/node]
//   pool -> final head
// ---------------------------------------------------------------------------

#define NBS 9            // 512 nodes per bucket
#define NPB 512
#define PART_TILE 4096   // edges per partition tile (256 thr x 16)
#define DBINS 64
#define STAGE_CAP 20480  // LDS-staged edges per bucket (80KB); mean ~8192

typedef __attribute__((ext_vector_type(8))) short short8;
typedef __attribute__((ext_vector_type(4))) float f32x4;

__device__ __forceinline__ float bf2f(unsigned short u) {
    return __uint_as_float(((unsigned int)u) << 16);
}
__device__ __forceinline__ unsigned short f2bf(float f) {
    unsigned int u = __float_as_uint(f);
    return (unsigned short)((u + 0x7FFFu + ((u >> 16) & 1u)) >> 16);
}
__device__ __forceinline__ float4 bfu4_to_f4(ushort4 v) {
    return make_float4(bf2f(v.x), bf2f(v.y), bf2f(v.z), bf2f(v.w));
}
__device__ __forceinline__ short8 pack_bf8(f32x4 a, f32x4 b) {
    short8 s;
    s[0] = (short)f2bf(a.x); s[1] = (short)f2bf(a.y);
    s[2] = (short)f2bf(a.z); s[3] = (short)f2bf(a.w);
    s[4] = (short)f2bf(b.x); s[5] = (short)f2bf(b.y);
    s[6] = (short)f2bf(b.z); s[7] = (short)f2bf(b.w);
    return s;
}
__device__ __forceinline__ void acc8(int4 v, float* a) {
    a[0] += __uint_as_float(((unsigned int)v.x) << 16);
    a[1] += __uint_as_float(((unsigned int)v.x) & 0xFFFF0000u);
    a[2] += __uint_as_float(((unsigned int)v.y) << 16);
    a[3] += __uint_as_float(((unsigned int)v.y) & 0xFFFF0000u);
    a[4] += __uint_as_float(((unsigned int)v.z) << 16);
    a[5] += __uint_as_float(((unsigned int)v.z) & 0xFFFF0000u);
    a[6] += __uint_as_float(((unsigned int)v.w) << 16);
    a[7] += __uint_as_float(((unsigned int)v.w) & 0xFFFF0000u);
}
__device__ __forceinline__ unsigned int pack2(float x, float y) {
    return (unsigned int)f2bf(x) | ((unsigned int)f2bf(y) << 16);
}

// ---------------- CSR build ----------------

__global__ __launch_bounds__(256) void bucket_count(const int* __restrict__ dst, int E,
                                                    int* __restrict__ bcnt, int B) {
    __shared__ int h[1024];
    for (int i = threadIdx.x; i < B; i += 256) h[i] = 0;
    __syncthreads();
    int i = blockIdx.x * 256 + threadIdx.x;
    int stride = gridDim.x * 256;
    for (; i < E; i += stride) atomicAdd(&h[dst[i] >> NBS], 1);
    __syncthreads();
    for (int i2 = threadIdx.x; i2 < B; i2 += 256)
        if (h[i2]) atomicAdd(&bcnt[i2], h[i2]);
}

__global__ __launch_bounds__(1024) void bscan_kernel(const int* __restrict__ bcnt,
                                                     int* __restrict__ bptr,
                                                     int* __restrict__ bcur, int B) {
    __shared__ int s[1024];
    int t = threadIdx.x;
    int v = (t < B) ? bcnt[t] : 0;
    s[t] = v;
    __syncthreads();
    for (int off = 1; off < 1024; off <<= 1) {
        int x = (t >= off) ? s[t - off] : 0;
        __syncthreads();
        s[t] += x;
        __syncthreads();
    }
    if (t < B) {
        int excl = s[t] - v;
        bptr[t] = excl;
        bcur[t] = excl;
    }
    if (t == 0) bptr[B] = s[1023];
}

__global__ __launch_bounds__(256) void partition_kernel(const int* __restrict__ src,
                                                        const int* __restrict__ dst, int E,
                                                        int* __restrict__ bcur,
                                                        unsigned int* __restrict__ pairs,
                                                        int B) {
    __shared__ int h[1024];
    __shared__ int rankbase[1024];
    int t = threadIdx.x;
    int tile0 = blockIdx.x * PART_TILE;
    for (int i = t; i < B; i += 256) h[i] = 0;
    __syncthreads();

    int bk[16];
    int rk[16];
    unsigned int pk[16];
#pragma unroll
    for (int j = 0; j < 16; ++j) {
        int idx = tile0 + j * 256 + t;
        bk[j] = -1;
        if (idx < E) {
            int d = dst[idx];
            int s = src[idx];
            bk[j] = d >> NBS;
            pk[j] = ((unsigned int)(d & (NPB - 1)) << 23) | (unsigned int)s;
            rk[j] = atomicAdd(&h[bk[j]], 1);
        }
    }
    __syncthreads();
    for (int i = t; i < B; i += 256) rankbase[i] = h[i] ? atomicAdd(&bcur[i], h[i]) : 0;
    __syncthreads();
#pragma unroll
    for (int j = 0; j < 16; ++j)
        if (bk[j] >= 0) pairs[rankbase[bk[j]] + rk[j]] = pk[j];
}

// fused: per-bucket hist + scan -> rp,dinv + scatter -> col (pairs staged in LDS)
__global__ __launch_bounds__(256) void bucket_finalize(const unsigned int* __restrict__ pairs,
                                                       const int* __restrict__ bptr,
                                                       int* __restrict__ rp,
                                                       float* __restrict__ dinv,
                                                       int* __restrict__ col, int N, int B) {
    __shared__ int c[NPB];
    __shared__ int sa[NPB];
    __shared__ int sb[NPB];
    __shared__ unsigned int stage[STAGE_CAP];
    int b = blockIdx.x;
    int s = bptr[b], e = bptr[b + 1];
    int cnt = e - s;
    bool fits = (cnt <= STAGE_CAP);
    for (int i = threadIdx.x; i < NPB; i += 256) c[i] = 0;
    __syncthreads();
    if (fits) {
        for (int i = threadIdx.x; i < cnt; i += 256) {
            unsigned int p = pairs[s + i];
            stage[i] = p;
            atomicAdd(&c[p >> 23], 1);
        }
    } else {
        for (int i = threadIdx.x; i < cnt; i += 256) atomicAdd(&c[pairs[s + i] >> 23], 1);
    }
    __syncthreads();
    for (int i = threadIdx.x; i < NPB; i += 256) sa[i] = c[i];
    __syncthreads();
    int* pin = sa;
    int* pout = sb;
    for (int off = 1; off < NPB; off <<= 1) {
        for (int i = threadIdx.x; i < NPB; i += 256)
            pout[i] = pin[i] + ((i >= off) ? pin[i - off] : 0);
        __syncthreads();
        int* tmp = pin; pin = pout; pout = tmp;
    }
    // pin = inclusive scan; pout free -> absolute cursor for scatter
    int base = b << NBS;
    for (int i = threadIdx.x; i < NPB; i += 256) {
        int excl = s + pin[i] - c[i];
        pout[i] = excl;
        int node = base + i;
        if (node < N) {
            rp[node] = excl;
            dinv[node] = rsqrtf((float)c[i] + 1.0f);
        }
    }
    __syncthreads();
    if (fits) {
        for (int i = threadIdx.x; i < cnt; i += 256) {
            unsigned int p = stage[i];
            int dL = (int)(p >> 23);
            int pos = atomicAdd(&pout[dL], 1);
            col[pos] = (int)(p & 0x7FFFFFu);
        }
    } else {
        for (int i = threadIdx.x; i < cnt; i += 256) {
            unsigned int p = pairs[s + i];
            int dL = (int)(p >> 23);
            int pos = atomicAdd(&pout[dL], 1);
            col[pos] = (int)(p & 0x7FFFFFu);
        }
    }
    if (b == B - 1 && threadIdx.x == 0) rp[N] = bptr[B];
}

// ---------------- degree permutation (counting sort, 64 bins) ----------------

__global__ __launch_bounds__(256) void deg_hist(const int* __restrict__ rp, int N,
                                                int* __restrict__ dh) {
    __shared__ int h[DBINS];
    if (threadIdx.x < DBINS) h[threadIdx.x] = 0;
    __syncthreads();
    int i = blockIdx.x * 256 + threadIdx.x;
    if (i < N) {
        int d = min(rp[i + 1] - rp[i], DBINS - 1);
        atomicAdd(&h[d], 1);
    }
    __syncthreads();
    if (threadIdx.x < DBINS && h[threadIdx.x]) atomicAdd(&dh[threadIdx.x], h[threadIdx.x]);
}

__global__ void deg_scan(const int* __restrict__ dh, int* __restrict__ dcur) {
    __shared__ int s[DBINS];
    int t = threadIdx.x;
    int v = dh[t];
    s[t] = v;
    __syncthreads();
    for (int off = 1; off < DBINS; off <<= 1) {
        int x = (t >= off) ? s[t - off] : 0;
        __syncthreads();
        s[t] += x;
        __syncthreads();
    }
    dcur[t] = s[t] - v;  // exclusive
}

__global__ __launch_bounds__(256) void deg_scatter(const int* __restrict__ rp, int N,
                                                   int* __restrict__ dcur,
                                                   int* __restrict__ perm) {
    __shared__ int h[DBINS];
    __shared__ int base[DBINS];
    if (threadIdx.x < DBINS) h[threadIdx.x] = 0;
    __syncthreads();
    int i = blockIdx.x * 256 + threadIdx.x;
    int d = -1, r = 0;
    if (i < N) {
        d = min(rp[i + 1] - rp[i], DBINS - 1);
        r = atomicAdd(&h[d], 1);
    }
    __syncthreads();
    if (threadIdx.x < DBINS) base[threadIdx.x] = h[threadIdx.x] ? atomicAdd(&dcur[threadIdx.x], h[threadIdx.x]) : 0;
    __syncthreads();
    if (i < N) perm[base[d] + r] = i;
}

// ---------------- GEMM (MFMA) ----------------

__global__ void wconv_kernel(const float* __restrict__ W1, const float* __restrict__ W2,
                             unsigned short* __restrict__ Wt1, unsigned short* __restrict__ Wt2) {
    const float* W = (blockIdx.x & 128) ? W2 : W1;
    unsigned short* Wt = (blockIdx.x & 128) ? Wt2 : Wt1;
    int n = blockIdx.x & 127;
    int k = threadIdx.x;
    Wt[n * 128 + k] = f2bf(W[k * 128 + n]);
}

template <bool A_F32>
__global__ __launch_bounds__(256) void gemm_mfma(const void* __restrict__ Ap,
                                                 const unsigned short* __restrict__ Wt,
                                                 const float* __restrict__ dinv,
                                                 unsigned short* __restrict__ C, int M) {
    __shared__ unsigned char lds[32768];
    int t = threadIdx.x;
#pragma unroll
    for (int i = 0; i < 8; ++i) {
        int c = t + i * 256;
        int row = c >> 4;
        int b = (c & 15) << 4;
        int4 v = ((const int4*)Wt)[c];
        *(int4*)&lds[row * 256 + (b ^ ((row & 7) << 4))] = v;
    }

    int lane = t & 63;
    int wv = t >> 6;
    int r0 = blockIdx.x * 128 + wv * 32;
    int l15 = lane & 15;
    int kg = lane >> 4;

    short8 af[2][4];
#pragma unroll
    for (int rf = 0; rf < 2; ++rf) {
        int row = r0 + rf * 16 + l15;
        row = row < M ? row : M - 1;
#pragma unroll
        for (int kk = 0; kk < 4; ++kk) {
            size_t eoff = (size_t)row * 128 + kk * 32 + kg * 8;
            if constexpr (A_F32) {
                const float* A = (const float*)Ap;
                f32x4 v0 = __builtin_nontemporal_load((const f32x4*)(A + eoff));
                f32x4 v1 = __builtin_nontemporal_load((const f32x4*)(A + eoff + 4));
                af[rf][kk] = pack_bf8(v0, v1);
            } else {
                af[rf][kk] = *(const short8*)((const unsigned short*)Ap + eoff);
            }
        }
    }
    __syncthreads();

    f32x4 acc[2][8];
#pragma unroll
    for (int rf = 0; rf < 2; ++rf)
#pragma unroll
        for (int cf = 0; cf < 8; ++cf) acc[rf][cf] = (f32x4)(0.f);

#pragma unroll
    for (int cf = 0; cf < 8; ++cf) {
        short8 bfr[4];
#pragma unroll
        for (int kk = 0; kk < 4; ++kk) {
            int brow = cf * 16 + l15;
            int bb = kk * 64 + kg * 16;
            bfr[kk] = *(const short8*)&lds[brow * 256 + (bb ^ ((brow & 7) << 4))];
        }
#pragma unroll
        for (int kk = 0; kk < 4; ++kk) {
#pragma unroll
            for (int rf = 0; rf < 2; ++rf)
                acc[rf][cf] = __builtin_amdgcn_mfma_f32_16x16x32_bf16(af[rf][kk], bfr[kk],
                                                                      acc[rf][cf], 0, 0, 0);
        }
    }

#pragma unroll
    for (int rf = 0; rf < 2; ++rf) {
#pragma unroll
        for (int r = 0; r < 4; ++r) {
            int row = r0 + rf * 16 + kg * 4 + r;
            if (row < M) {
                float dv = dinv[row];
#pragma unroll
                for (int cf = 0; cf < 8; ++cf)
                    C[(size_t)row * 128 + cf * 16 + l15] = f2bf(acc[rf][cf][r] * dv);
            }
        }
    }
}

// ---------------- aggregation / pool / head ----------------

// 16 lanes per node (dwordx4), 4 nodes/wave, DESCENDING degree order
__global__ __launch_bounds__(256) void agg_q16(const unsigned short* __restrict__ hs,
                                               const float* __restrict__ dinv,
                                               const int* __restrict__ rp,
                                               const int* __restrict__ col,
                                               const int* __restrict__ perm,
                                               const float* __restrict__ bias,
                                               unsigned short* __restrict__ out, int N) {
    int q = (int)((blockIdx.x * 256 + threadIdx.x) >> 4);
    int l = threadIdx.x & 15;
    if (q >= N) return;
    int g = perm[N - 1 - q];  // heavy nodes first
    const int4* h4 = (const int4*)hs;

    float a[8];
    {
        int4 sv = h4[(size_t)g * 16 + l];  // self (hs_i)
        a[0] = __uint_as_float(((unsigned int)sv.x) << 16);
        a[1] = __uint_as_float(((unsigned int)sv.x) & 0xFFFF0000u);
        a[2] = __uint_as_float(((unsigned int)sv.y) << 16);
        a[3] = __uint_as_float(((unsigned int)sv.y) & 0xFFFF0000u);
        a[4] = __uint_as_float(((unsigned int)sv.z) << 16);
        a[5] = __uint_as_float(((unsigned int)sv.z) & 0xFFFF0000u);
        a[6] = __uint_as_float(((unsigned int)sv.w) << 16);
        a[7] = __uint_as_float(((unsigned int)sv.w) & 0xFFFF0000u);
    }

    int e = rp[g], end = rp[g + 1];
    for (; e + 7 < end; e += 8) {
        int j0 = col[e + 0], j1 = col[e + 1], j2 = col[e + 2], j3 = col[e + 3];
        int j4 = col[e + 4], j5 = col[e + 5], j6 = col[e + 6], j7 = col[e + 7];
        int4 v0 = h4[(size_t)j0 * 16 + l];
        int4 v1 = h4[(size_t)j1 * 16 + l];
        int4 v2 = h4[(size_t)j2 * 16 + l];
        int4 v3 = h4[(size_t)j3 * 16 + l];
        int4 v4 = h4[(size_t)j4 * 16 + l];
        int4 v5 = h4[(size_t)j5 * 16 + l];
        int4 v6 = h4[(size_t)j6 * 16 + l];
        int4 v7 = h4[(size_t)j7 * 16 + l];
        acc8(v0, a); acc8(v1, a); acc8(v2, a); acc8(v3, a);
        acc8(v4, a); acc8(v5, a); acc8(v6, a); acc8(v7, a);
    }
    for (; e + 1 < end; e += 2) {
        int j0 = col[e], j1 = col[e + 1];
        int4 v0 = h4[(size_t)j0 * 16 + l];
        int4 v1 = h4[(size_t)j1 * 16 + l];
        acc8(v0, a); acc8(v1, a);
    }
    if (e < end) {
        int j = col[e];
        acc8(h4[(size_t)j * 16 + l], a);
    }

    float dv = dinv[g];
    float4 b0 = ((const float4*)bias)[l * 2];
    float4 b1 = ((const float4*)bias)[l * 2 + 1];
    int4 o;
    o.x = (int)pack2(fmaxf(fmaf(a[0], dv, b0.x), 0.f), fmaxf(fmaf(a[1], dv, b0.y), 0.f));
    o.y = (int)pack2(fmaxf(fmaf(a[2], dv, b0.z), 0.f), fmaxf(fmaf(a[3], dv, b0.w), 0.f));
    o.z = (int)pack2(fmaxf(fmaf(a[4], dv, b1.x), 0.f), fmaxf(fmaf(a[5], dv, b1.y), 0.f));
    o.w = (int)pack2(fmaxf(fmaf(a[6], dv, b1.z), 0.f), fmaxf(fmaf(a[7], dv, b1.w), 0.f));
    ((int4*)out)[(size_t)g * 16 + l] = o;
}

__global__ __launch_bounds__(256) void pool_bf16(const unsigned short* __restrict__ r2,
                                                 const int* __restrict__ batch,
                                                 float* __restrict__ ps,
                                                 int* __restrict__ pc, int N) {
    int grp = (int)((blockIdx.x * 256 + threadIdx.x) >> 5);
    int lane = threadIdx.x & 31;
    int n0 = grp * 32;
    if (n0 >= N) return;
    int n1 = min(n0 + 32, N);
    const ushort4* r4 = (const ushort4*)r2;
    float4 acc = make_float4(0.f, 0.f, 0.f, 0.f);
    int curg = batch[n0];
    int cnt = 0;
    for (int n = n0; n < n1; ++n) {
        int gph = batch[n];
        if (gph != curg) {
            atomicAdd(&ps[curg * 128 + lane * 4 + 0], acc.x);
            atomicAdd(&ps[curg * 128 + lane * 4 + 1], acc.y);
            atomicAdd(&ps[curg * 128 + lane * 4 + 2], acc.z);
            atomicAdd(&ps[curg * 128 + lane * 4 + 3], acc.w);
            if (lane == 0) atomicAdd(&pc[curg], cnt);
            acc = make_float4(0.f, 0.f, 0.f, 0.f);
            cnt = 0;
            curg = gph;
        }
        float4 v = bfu4_to_f4(r4[(size_t)n * 32 + lane]);
        acc.x += v.x;
        acc.y += v.y;
        acc.z += v.z;
        acc.w += v.w;
        cnt++;
    }
    atomicAdd(&ps[curg * 128 + lane * 4 + 0], acc.x);
    atomicAdd(&ps[curg * 128 + lane * 4 + 1], acc.y);
    atomicAdd(&ps[curg * 128 + lane * 4 + 2], acc.z);
    atomicAdd(&ps[curg * 128 + lane * 4 + 3], acc.w);
    if (lane == 0) atomicAdd(&pc[curg], cnt);
}

__global__ __launch_bounds__(256) void final_kernel(const float* __restrict__ ps,
                                                    const int* __restrict__ pc,
                                                    const float* __restrict__ Wlin,
                                                    const float* __restrict__ blin,
                                                    float* __restrict__ out, int G) {
    int g = (int)((blockIdx.x * 256 + threadIdx.x) >> 6);
    int lane = threadIdx.x & 63;
    if (g >= G) return;
    float2 s = ((const float2*)ps)[g * 64 + lane];
    float2 w = ((const float2*)Wlin)[lane];
    float v = s.x * w.x + s.y * w.y;
#pragma unroll
    for (int off = 32; off > 0; off >>= 1) v += __shfl_down(v, off);
    if (lane == 0) {
        float c = (float)max(pc[g], 1);
        out[g] = v / c + blin[0];
    }
}

extern "C" void kernel_launch(void* const* d_in, const int* in_sizes, int n_in,
                              void* d_out, int out_size, void* d_ws, size_t ws_size,
                              hipStream_t stream) {
    const float* x    = (const float*)d_in[0];
    const float* W1   = (const float*)d_in[1];
    const float* b1   = (const float*)d_in[2];
    const float* W2   = (const float*)d_in[3];
    const float* b2   = (const float*)d_in[4];
    const float* Wlin = (const float*)d_in[5];
    const float* blin = (const float*)d_in[6];
    const int*   ei   = (const int*)d_in[7];   // [2, E]
    const int*   batch= (const int*)d_in[8];   // [N]

    const int N = in_sizes[0] / 128;
    const int E = in_sizes[7] / 2;
    const int G = out_size;
    const int B = (N + NPB - 1) >> NBS;

    const int* srcp = ei;
    const int* dstp = ei + E;

    char* w = (char*)d_ws;
    size_t off = 0;
    auto carve = [&](size_t bytes) {
        size_t o = off;
        off = (off + bytes + 255) & ~(size_t)255;
        return (void*)(w + o);
    };
    unsigned short* bufA = (unsigned short*)carve((size_t)N * 128 * 2);
    unsigned short* bufB = (unsigned short*)carve((size_t)N * 128 * 2);
    float* dinv = (float*)carve((size_t)N * 4);
    int*   rp   = (int*)carve((size_t)(N + 1) * 4);
    int*   col  = (int*)carve((size_t)E * 4);
    unsigned int* pairs = (unsigned int*)carve((size_t)E * 4);
    int*   bcnt = (int*)carve((size_t)(B + 1) * 4);
    int*   bptr = (int*)carve((size_t)(B + 1) * 4);
    int*   bcur = (int*)carve((size_t)(B + 1) * 4);
    int*   perm = (int*)carve((size_t)N * 4);
    int*   dh   = (int*)carve(DBINS * 4);
    int*   dcur = (int*)carve(DBINS * 4);
    unsigned short* Wt1 = (unsigned short*)carve(128 * 128 * 2);
    unsigned short* Wt2 = (unsigned short*)carve(128 * 128 * 2);
    float* ps   = (float*)carve((size_t)G * 128 * 4);
    int*   pc   = (int*)carve((size_t)G * 4);
    (void)ws_size;

    const int ntiles = (E + PART_TILE - 1) / PART_TILE;
    const int nblk = (N + 255) / 256;

    // CSR build (binned)
    hipMemsetAsync(bcnt, 0, (size_t)(B + 1) * 4, stream);
    bucket_count<<<1024, 256, 0, stream>>>(dstp, E, bcnt, B);
    bscan_kernel<<<1, 1024, 0, stream>>>(bcnt, bptr, bcur, B);
    partition_kernel<<<ntiles, 256, 0, stream>>>(srcp, dstp, E, bcur, pairs, B);
    bucket_finalize<<<B, 256, 0, stream>>>(pairs, bptr, rp, dinv, col, N, B);

    // degree permutation
    hipMemsetAsync(dh, 0, DBINS * 4, stream);
    deg_hist<<<nblk, 256, 0, stream>>>(rp, N, dh);
    deg_scan<<<1, DBINS, 0, stream>>>(dh, dcur);
    deg_scatter<<<nblk, 256, 0, stream>>>(rp, N, dcur, perm);

    // weight transpose+convert (both layers)
    wconv_kernel<<<256, 128, 0, stream>>>(W1, W2, Wt1, Wt2);

    const int gemm_grid = (N + 127) / 128;
    const int agg_grid  = (int)(((size_t)N * 16 + 255) / 256);

    // layer 1
    gemm_mfma<true><<<gemm_grid, 256, 0, stream>>>(x, Wt1, dinv, bufA, N);
    agg_q16<<<agg_grid, 256, 0, stream>>>(bufA, dinv, rp, col, perm, b1, bufB, N);
    // layer 2
    gemm_mfma<false><<<gemm_grid, 256, 0, stream>>>(bufB, Wt2, dinv, bufA, N);
    agg_q16<<<agg_grid, 256, 0, stream>>>(bufA, dinv, rp, col, perm, b2, bufB, N);

    // pooling
    hipMemsetAsync(ps, 0, (size_t)G * 128 * 4, stream);
    hipMemsetAsync(pc, 0, (size_t)G * 4, stream);
    const int ngrp = (N + 31) / 32;
    pool_bf16<<<(int)(((size_t)ngrp * 32 + 255) / 256), 256, 0, stream>>>(bufB, batch, ps, pc, N);

    final_kernel<<<(G * 64 + 255) / 256, 256, 0, stream>>>(ps, pc, Wlin, blin, (float*)d_out, G);
}